// Round 1
// baseline (648.352 us; speedup 1.0000x reference)
//
#include <hip/hip_runtime.h>
#include <hip/hip_bf16.h>

// Sizes (fixed by the problem)
#define D_IN   256
#define D_OUT  16

// ---------------------------------------------------------------------------
// Kernel 1: x_lin = x @ W   (x: [n_src,256] f32, W: [256,16] f32)
// Thread handles one row and 4 output cols. x read as float4 (coalesced /
// broadcast within wave); W reads are same-address across rows -> L1 broadcast.
// ---------------------------------------------------------------------------
__global__ __launch_bounds__(256) void xlin_kernel(
    const float* __restrict__ x, const float* __restrict__ W,
    float* __restrict__ xlin, int n_src) {
  int tid = blockIdx.x * 256 + threadIdx.x;
  int row = tid >> 2;            // 4 col-groups per row
  int cg  = (tid & 3) * 4;       // col base: 0,4,8,12
  if (row >= n_src) return;
  const float4* xr = reinterpret_cast<const float4*>(x + (size_t)row * D_IN);
  float4 acc = make_float4(0.f, 0.f, 0.f, 0.f);
#pragma unroll 4
  for (int k4 = 0; k4 < D_IN / 4; ++k4) {
    float4 xv = xr[k4];
    float4 w0 = *reinterpret_cast<const float4*>(W + (size_t)(k4 * 4 + 0) * D_OUT + cg);
    float4 w1 = *reinterpret_cast<const float4*>(W + (size_t)(k4 * 4 + 1) * D_OUT + cg);
    float4 w2 = *reinterpret_cast<const float4*>(W + (size_t)(k4 * 4 + 2) * D_OUT + cg);
    float4 w3 = *reinterpret_cast<const float4*>(W + (size_t)(k4 * 4 + 3) * D_OUT + cg);
    acc.x += xv.x * w0.x + xv.y * w1.x + xv.z * w2.x + xv.w * w3.x;
    acc.y += xv.x * w0.y + xv.y * w1.y + xv.z * w2.y + xv.w * w3.y;
    acc.z += xv.x * w0.z + xv.y * w1.z + xv.z * w2.z + xv.w * w3.z;
    acc.w += xv.x * w0.w + xv.y * w1.w + xv.z * w2.w + xv.w * w3.w;
  }
  *reinterpret_cast<float4*>(xlin + (size_t)row * D_OUT + cg) = acc;
}

// ---------------------------------------------------------------------------
// Kernel 2: degree histograms (float accumulators)
// idx arrays may be stored as int32 (stride 1) or int64 (stride 2, little-
// endian low word read). Values < 2^31 so low word is exact.
// ---------------------------------------------------------------------------
__global__ __launch_bounds__(256) void deg_kernel(
    const int* __restrict__ es, const int* __restrict__ ed,
    float* __restrict__ deg_src, float* __restrict__ deg_dst,
    int n_edges, int stride) {
  int e = blockIdx.x * 256 + threadIdx.x;
  if (e >= n_edges) return;
  int s = es[(size_t)e * stride];
  int d = ed[(size_t)e * stride];
  atomicAdd(&deg_src[s], 1.0f);
  atomicAdd(&deg_dst[d], 1.0f);
}

// ---------------------------------------------------------------------------
// Kernel 3: edge scatter. 16 threads per edge (one per output col).
// msg = rsqrt((deg_src[s]+1)(deg_dst[d]+1)) * xlin[s][c]  -> atomicAdd agg[d][c]
// agg lives in d_out (zeroed first).
// ---------------------------------------------------------------------------
__global__ __launch_bounds__(256) void edge_kernel(
    const int* __restrict__ es, const int* __restrict__ ed,
    const float* __restrict__ xlin,
    const float* __restrict__ deg_src, const float* __restrict__ deg_dst,
    float* __restrict__ agg, int n_edges, int stride) {
  int t = blockIdx.x * 256 + threadIdx.x;
  int e = t >> 4;
  int c = t & 15;
  if (e >= n_edges) return;
  int s = es[(size_t)e * stride];
  int d = ed[(size_t)e * stride];
  float norm = rsqrtf((deg_src[s] + 1.0f) * (deg_dst[d] + 1.0f));
  float v = norm * xlin[(size_t)s * D_OUT + c];
  atomicAdd(&agg[(size_t)d * D_OUT + c], v);
}

// ---------------------------------------------------------------------------
// Kernel 4: finalize: out = log_softmax(agg + xlin[res]/(deg_dst+1) + b)
// 16 lanes per row; shuffle reduce within 16-lane groups.
// ---------------------------------------------------------------------------
__global__ __launch_bounds__(256) void finalize_kernel(
    const float* __restrict__ xlin, const int* __restrict__ rn,
    const float* __restrict__ deg_dst, const float* __restrict__ b,
    float* __restrict__ out, int n_dst, int stride) {
  int t = blockIdx.x * 256 + threadIdx.x;
  int row = t >> 4;
  int c = t & 15;
  if (row >= n_dst) return;
  int r = rn[(size_t)row * stride];
  float v = out[(size_t)row * D_OUT + c]
          + xlin[(size_t)r * D_OUT + c] / (deg_dst[row] + 1.0f)
          + b[c];
  // log-softmax across the 16 cols (16-lane shuffle groups)
  float m = v;
#pragma unroll
  for (int off = 1; off < 16; off <<= 1) m = fmaxf(m, __shfl_xor(m, off, 16));
  float ex = expf(v - m);
  float sum = ex;
#pragma unroll
  for (int off = 1; off < 16; off <<= 1) sum += __shfl_xor(sum, off, 16);
  out[(size_t)row * D_OUT + c] = v - m - logf(sum);
}

extern "C" void kernel_launch(void* const* d_in, const int* in_sizes, int n_in,
                              void* d_out, int out_size, void* d_ws, size_t ws_size,
                              hipStream_t stream) {
  const float* x  = (const float*)d_in[0];
  const float* W  = (const float*)d_in[1];
  const float* b  = (const float*)d_in[2];
  const int*   es = (const int*)d_in[3];
  const int*   ed = (const int*)d_in[4];
  const int*   rn = (const int*)d_in[5];
  float* out = (float*)d_out;

  const int n_src = in_sizes[0] / D_IN;        // 200000
  const int n_dst = out_size / D_OUT;          // 50000
  // int64 may arrive as 2 words per element; detect via element count.
  const int e_elems = in_sizes[3];
  const int n_edges = (e_elems == 2 * in_sizes[4] || e_elems % 2 == 0) ? 0 : 0; // placeholder
  // Robust detection: edges count is 1.6M; if array has 3.2M words it's int64.
  int stride_e = 1, n_e = in_sizes[3];
  if (in_sizes[3] == in_sizes[4] && in_sizes[3] == 3200000) { stride_e = 2; n_e = 1600000; }
  int stride_r = 1, n_r = in_sizes[5];
  if (in_sizes[5] == 2 * n_dst) { stride_r = 2; n_r = n_dst; }
  (void)n_edges; (void)e_elems; (void)n_r;

  // Workspace layout: xlin [n_src*16] | deg_src [n_src] | deg_dst [n_dst]
  float* xlin    = (float*)d_ws;
  float* deg_src = xlin + (size_t)n_src * D_OUT;
  float* deg_dst = deg_src + n_src;

  hipMemsetAsync(deg_src, 0, (size_t)(n_src + n_dst) * sizeof(float), stream);
  hipMemsetAsync(d_out, 0, (size_t)out_size * sizeof(float), stream);

  // 1) x_lin
  {
    int threads = n_src * 4;
    int grid = (threads + 255) / 256;
    xlin_kernel<<<grid, 256, 0, stream>>>(x, W, xlin, n_src);
  }
  // 2) degrees
  {
    int grid = (n_e + 255) / 256;
    deg_kernel<<<grid, 256, 0, stream>>>(es, ed, deg_src, deg_dst, n_e, stride_e);
  }
  // 3) edge scatter into d_out (acts as agg)
  {
    long long threads = (long long)n_e * D_OUT;
    int grid = (int)((threads + 255) / 256);
    edge_kernel<<<grid, 256, 0, stream>>>(es, ed, xlin, deg_src, deg_dst, out, n_e, stride_e);
  }
  // 4) finalize + log-softmax (in place on d_out)
  {
    int threads = n_dst * D_OUT;
    int grid = (threads + 255) / 256;
    finalize_kernel<<<grid, 256, 0, stream>>>(xlin, rn, deg_dst, b, out, n_dst, stride_r);
  }
}

// Round 4
// 602.013 us; speedup vs baseline: 1.0770x; 1.0770x over previous
//
#include <hip/hip_runtime.h>
#include <hip/hip_bf16.h>

#define D_IN   256
#define D_OUT  16

__device__ __forceinline__ void acc4(float4& a, float xs, const float4& wv) {
  a.x += xs * wv.x; a.y += xs * wv.y; a.z += xs * wv.z; a.w += xs * wv.w;
}

// ---------------------------------------------------------------------------
// Kernel 1: x_lin = x @ W   (x: [n_src,256] f32, W: [256,16] f32)
// k-sliced scheme: thread = (kg, cg, wave). kg in [0,16) slices K, cg in [0,4)
// slices output cols (4 each). Each thread holds its W fragment (16 k x 4 col
// = 16 float4) in registers, loaded once. x is read exactly once, coalesced
// (16-lane group reads 256B contiguous per j). Cross-lane reduce over the 16
// kg lanes via shfl_xor; lane kg==0 writes float4.
// ---------------------------------------------------------------------------
__global__ __launch_bounds__(256) void xlin_kernel(
    const float* __restrict__ x, const float* __restrict__ W,
    float* __restrict__ xlin, int n_src, int total_waves) {
  const int kg = threadIdx.x & 15;
  const int cg = (threadIdx.x >> 4) & 3;
  const int wv = threadIdx.x >> 6;
  const int gw = blockIdx.x * 4 + wv;

  // W fragment: rows 4*kg + 64*j + jj, cols cg*4 .. cg*4+3
  float4 wf[4][4];
#pragma unroll
  for (int j = 0; j < 4; ++j)
#pragma unroll
    for (int jj = 0; jj < 4; ++jj) {
      int r = 4 * kg + 64 * j + jj;
      wf[j][jj] = *reinterpret_cast<const float4*>(W + r * D_OUT + cg * 4);
    }

  const int npairs = n_src >> 1;
  for (int p = gw; p < npairs; p += total_waves) {
    const int r0 = 2 * p, r1 = 2 * p + 1;
    float4 xv0[4], xv1[4];
#pragma unroll
    for (int j = 0; j < 4; ++j) {
      xv0[j] = *reinterpret_cast<const float4*>(x + (size_t)r0 * D_IN + (kg + 16 * j) * 4);
      xv1[j] = *reinterpret_cast<const float4*>(x + (size_t)r1 * D_IN + (kg + 16 * j) * 4);
    }
    float4 a0 = make_float4(0.f, 0.f, 0.f, 0.f);
    float4 a1 = make_float4(0.f, 0.f, 0.f, 0.f);
#pragma unroll
    for (int j = 0; j < 4; ++j) {
      acc4(a0, xv0[j].x, wf[j][0]); acc4(a1, xv1[j].x, wf[j][0]);
      acc4(a0, xv0[j].y, wf[j][1]); acc4(a1, xv1[j].y, wf[j][1]);
      acc4(a0, xv0[j].z, wf[j][2]); acc4(a1, xv1[j].z, wf[j][2]);
      acc4(a0, xv0[j].w, wf[j][3]); acc4(a1, xv1[j].w, wf[j][3]);
    }
    // reduce across the 16 kg lanes
#pragma unroll
    for (int off = 1; off < 16; off <<= 1) {
      a0.x += __shfl_xor(a0.x, off, 16); a0.y += __shfl_xor(a0.y, off, 16);
      a0.z += __shfl_xor(a0.z, off, 16); a0.w += __shfl_xor(a0.w, off, 16);
      a1.x += __shfl_xor(a1.x, off, 16); a1.y += __shfl_xor(a1.y, off, 16);
      a1.z += __shfl_xor(a1.z, off, 16); a1.w += __shfl_xor(a1.w, off, 16);
    }
    if (kg == 0) {
      *reinterpret_cast<float4*>(xlin + (size_t)r0 * D_OUT + cg * 4) = a0;
      *reinterpret_cast<float4*>(xlin + (size_t)r1 * D_OUT + cg * 4) = a1;
    }
  }
}

// ---------------------------------------------------------------------------
// Kernel 2: degree histograms (float accumulators)
// ---------------------------------------------------------------------------
__global__ __launch_bounds__(256) void deg_kernel(
    const int* __restrict__ es, const int* __restrict__ ed,
    float* __restrict__ deg_src, float* __restrict__ deg_dst,
    int n_edges, int stride) {
  int e = blockIdx.x * 256 + threadIdx.x;
  if (e >= n_edges) return;
  int s = es[(size_t)e * stride];
  int d = ed[(size_t)e * stride];
  atomicAdd(&deg_src[s], 1.0f);
  atomicAdd(&deg_dst[d], 1.0f);
}

// ---------------------------------------------------------------------------
// Kernel 3: edge scatter. 16 threads per edge (one per output col).
// ---------------------------------------------------------------------------
__global__ __launch_bounds__(256) void edge_kernel(
    const int* __restrict__ es, const int* __restrict__ ed,
    const float* __restrict__ xlin,
    const float* __restrict__ deg_src, const float* __restrict__ deg_dst,
    float* __restrict__ agg, int n_edges, int stride) {
  int t = blockIdx.x * 256 + threadIdx.x;
  int e = t >> 4;
  int c = t & 15;
  if (e >= n_edges) return;
  int s = es[(size_t)e * stride];
  int d = ed[(size_t)e * stride];
  float norm = rsqrtf((deg_src[s] + 1.0f) * (deg_dst[d] + 1.0f));
  float v = norm * xlin[(size_t)s * D_OUT + c];
  atomicAdd(&agg[(size_t)d * D_OUT + c], v);
}

// ---------------------------------------------------------------------------
// Kernel 4: finalize: out = log_softmax(agg + xlin[res]/(deg_dst+1) + b)
// ---------------------------------------------------------------------------
__global__ __launch_bounds__(256) void finalize_kernel(
    const float* __restrict__ xlin, const int* __restrict__ rn,
    const float* __restrict__ deg_dst, const float* __restrict__ b,
    float* __restrict__ out, int n_dst, int stride) {
  int t = blockIdx.x * 256 + threadIdx.x;
  int row = t >> 4;
  int c = t & 15;
  if (row >= n_dst) return;
  int r = rn[(size_t)row * stride];
  float v = out[(size_t)row * D_OUT + c]
          + xlin[(size_t)r * D_OUT + c] / (deg_dst[row] + 1.0f)
          + b[c];
  float m = v;
#pragma unroll
  for (int off = 1; off < 16; off <<= 1) m = fmaxf(m, __shfl_xor(m, off, 16));
  float ex = expf(v - m);
  float sum = ex;
#pragma unroll
  for (int off = 1; off < 16; off <<= 1) sum += __shfl_xor(sum, off, 16);
  out[(size_t)row * D_OUT + c] = v - m - logf(sum);
}

extern "C" void kernel_launch(void* const* d_in, const int* in_sizes, int n_in,
                              void* d_out, int out_size, void* d_ws, size_t ws_size,
                              hipStream_t stream) {
  const float* x  = (const float*)d_in[0];
  const float* W  = (const float*)d_in[1];
  const float* b  = (const float*)d_in[2];
  const int*   es = (const int*)d_in[3];
  const int*   ed = (const int*)d_in[4];
  const int*   rn = (const int*)d_in[5];
  float* out = (float*)d_out;

  const int n_src = in_sizes[0] / D_IN;        // 200000
  const int n_dst = out_size / D_OUT;          // 50000

  // int64 indices arrive as 2 words per element; detect via element count.
  int stride_e = 1, n_e = in_sizes[3];
  if (in_sizes[3] == 3200000) { stride_e = 2; n_e = 1600000; }
  int stride_r = 1;
  if (in_sizes[5] == 2 * n_dst) { stride_r = 2; }

  // Workspace layout: xlin [n_src*16] | deg_src [n_src] | deg_dst [n_dst]
  float* xlin    = (float*)d_ws;
  float* deg_src = xlin + (size_t)n_src * D_OUT;
  float* deg_dst = deg_src + n_src;

  (void)hipMemsetAsync(deg_src, 0, (size_t)(n_src + n_dst) * sizeof(float), stream);
  (void)hipMemsetAsync(d_out, 0, (size_t)out_size * sizeof(float), stream);

  // 1) x_lin  (grid: 1024 blocks = 4096 waves; each wave strides over row pairs)
  {
    const int grid = 1024;
    xlin_kernel<<<grid, 256, 0, stream>>>(x, W, xlin, n_src, grid * 4);
  }
  // 2) degrees
  {
    int grid = (n_e + 255) / 256;
    deg_kernel<<<grid, 256, 0, stream>>>(es, ed, deg_src, deg_dst, n_e, stride_e);
  }
  // 3) edge scatter into d_out (acts as agg)
  {
    long long threads = (long long)n_e * D_OUT;
    int grid = (int)((threads + 255) / 256);
    edge_kernel<<<grid, 256, 0, stream>>>(es, ed, xlin, deg_src, deg_dst, out, n_e, stride_e);
  }
  // 4) finalize + log-softmax (in place on d_out)
  {
    int threads = n_dst * D_OUT;
    int grid = (threads + 255) / 256;
    finalize_kernel<<<grid, 256, 0, stream>>>(xlin, rn, deg_dst, b, out, n_dst, stride_r);
  }
}

// Round 5
// 513.330 us; speedup vs baseline: 1.2630x; 1.1728x over previous
//
#include <hip/hip_runtime.h>
#include <hip/hip_bf16.h>

#define D_IN   256
#define D_OUT  16

__device__ __forceinline__ void acc4(float4& a, float xs, const float4& wv) {
  a.x += xs * wv.x; a.y += xs * wv.y; a.z += xs * wv.z; a.w += xs * wv.w;
}

// ---------------------------------------------------------------------------
// Kernel 1 (fused): x_lin = x @ W  AND  deg_src histogram.
// Phase A: k-sliced GEMV (thread = kg in [0,16) K-slice, cg in [0,4) col-slice;
//          W fragment in registers; x read once, coalesced; shfl_xor reduce).
// Phase B: grid-stride over edges, atomicAdd(&deg_src[src], 1).
// The two phases write disjoint outputs; co-resident blocks at different
// phases overlap atomic latency with GEMV compute.
// ---------------------------------------------------------------------------
__global__ __launch_bounds__(256) void xlin_deg_kernel(
    const float* __restrict__ x, const float* __restrict__ W,
    float* __restrict__ xlin, const int* __restrict__ es,
    float* __restrict__ deg_src,
    int n_src, int n_edges, int stride, int nblocks) {
  const int kg = threadIdx.x & 15;
  const int cg = (threadIdx.x >> 4) & 3;
  const int wv = threadIdx.x >> 6;
  const int gw = blockIdx.x * 4 + wv;
  const int total_waves = nblocks * 4;

  // W fragment: rows 4*kg + 64*j + jj, cols cg*4 .. cg*4+3
  float4 wf[4][4];
#pragma unroll
  for (int j = 0; j < 4; ++j)
#pragma unroll
    for (int jj = 0; jj < 4; ++jj) {
      int r = 4 * kg + 64 * j + jj;
      wf[j][jj] = *reinterpret_cast<const float4*>(W + r * D_OUT + cg * 4);
    }

  const int npairs = n_src >> 1;
  for (int p = gw; p < npairs; p += total_waves) {
    const int r0 = 2 * p, r1 = 2 * p + 1;
    float4 xv0[4], xv1[4];
#pragma unroll
    for (int j = 0; j < 4; ++j) {
      xv0[j] = *reinterpret_cast<const float4*>(x + (size_t)r0 * D_IN + (kg + 16 * j) * 4);
      xv1[j] = *reinterpret_cast<const float4*>(x + (size_t)r1 * D_IN + (kg + 16 * j) * 4);
    }
    float4 a0 = make_float4(0.f, 0.f, 0.f, 0.f);
    float4 a1 = make_float4(0.f, 0.f, 0.f, 0.f);
#pragma unroll
    for (int j = 0; j < 4; ++j) {
      acc4(a0, xv0[j].x, wf[j][0]); acc4(a1, xv1[j].x, wf[j][0]);
      acc4(a0, xv0[j].y, wf[j][1]); acc4(a1, xv1[j].y, wf[j][1]);
      acc4(a0, xv0[j].z, wf[j][2]); acc4(a1, xv1[j].z, wf[j][2]);
      acc4(a0, xv0[j].w, wf[j][3]); acc4(a1, xv1[j].w, wf[j][3]);
    }
#pragma unroll
    for (int off = 1; off < 16; off <<= 1) {
      a0.x += __shfl_xor(a0.x, off, 16); a0.y += __shfl_xor(a0.y, off, 16);
      a0.z += __shfl_xor(a0.z, off, 16); a0.w += __shfl_xor(a0.w, off, 16);
      a1.x += __shfl_xor(a1.x, off, 16); a1.y += __shfl_xor(a1.y, off, 16);
      a1.z += __shfl_xor(a1.z, off, 16); a1.w += __shfl_xor(a1.w, off, 16);
    }
    if (kg == 0) {
      *reinterpret_cast<float4*>(xlin + (size_t)r0 * D_OUT + cg * 4) = a0;
      *reinterpret_cast<float4*>(xlin + (size_t)r1 * D_OUT + cg * 4) = a1;
    }
  }

  // Phase B: deg_src histogram (grid-stride)
  for (int e = blockIdx.x * 256 + threadIdx.x; e < n_edges; e += nblocks * 256) {
    int s = es[(size_t)e * stride];
    atomicAdd(&deg_src[s], 1.0f);
  }
}

// ---------------------------------------------------------------------------
// Kernel 2: edge scatter (16 lanes per edge, one 64B line-RMW per edge) plus
// deg_dst counting from lane 0. m[d] += rsqrt(deg_src[s]+1) * xlin[s];
// the rsqrt(deg_dst+1) factor is applied in finalize (constant per row).
// ---------------------------------------------------------------------------
__global__ __launch_bounds__(256) void edge_kernel(
    const int* __restrict__ es, const int* __restrict__ ed,
    const float* __restrict__ xlin, const float* __restrict__ deg_src,
    float* __restrict__ m, float* __restrict__ deg_dst,
    int n_edges, int stride) {
  int t = blockIdx.x * 256 + threadIdx.x;
  int e = t >> 4;
  int c = t & 15;
  if (e >= n_edges) return;
  int s = es[(size_t)e * stride];
  int d = ed[(size_t)e * stride];
  float v = rsqrtf(deg_src[s] + 1.0f) * xlin[(size_t)s * D_OUT + c];
  atomicAdd(&m[(size_t)d * D_OUT + c], v);
  if (c == 0) atomicAdd(&deg_dst[d], 1.0f);
}

// ---------------------------------------------------------------------------
// Kernel 3: finalize: out = log_softmax(m*rsqrt(dd+1) + xlin[res]/(dd+1) + b)
// ---------------------------------------------------------------------------
__global__ __launch_bounds__(256) void finalize_kernel(
    const float* __restrict__ xlin, const int* __restrict__ rn,
    const float* __restrict__ deg_dst, const float* __restrict__ b,
    float* __restrict__ out, int n_dst, int stride) {
  int t = blockIdx.x * 256 + threadIdx.x;
  int row = t >> 4;
  int c = t & 15;
  if (row >= n_dst) return;
  int r = rn[(size_t)row * stride];
  float dd = deg_dst[row];
  float v = out[(size_t)row * D_OUT + c] * rsqrtf(dd + 1.0f)
          + xlin[(size_t)r * D_OUT + c] / (dd + 1.0f)
          + b[c];
  float mx = v;
#pragma unroll
  for (int off = 1; off < 16; off <<= 1) mx = fmaxf(mx, __shfl_xor(mx, off, 16));
  float ex = expf(v - mx);
  float sum = ex;
#pragma unroll
  for (int off = 1; off < 16; off <<= 1) sum += __shfl_xor(sum, off, 16);
  out[(size_t)row * D_OUT + c] = v - mx - logf(sum);
}

extern "C" void kernel_launch(void* const* d_in, const int* in_sizes, int n_in,
                              void* d_out, int out_size, void* d_ws, size_t ws_size,
                              hipStream_t stream) {
  const float* x  = (const float*)d_in[0];
  const float* W  = (const float*)d_in[1];
  const float* b  = (const float*)d_in[2];
  const int*   es = (const int*)d_in[3];
  const int*   ed = (const int*)d_in[4];
  const int*   rn = (const int*)d_in[5];
  float* out = (float*)d_out;

  const int n_src = in_sizes[0] / D_IN;        // 200000
  const int n_dst = out_size / D_OUT;          // 50000

  // int64 indices arrive as 2 words per element; detect via element count.
  int stride_e = 1, n_e = in_sizes[3];
  if (in_sizes[3] == 3200000) { stride_e = 2; n_e = 1600000; }
  int stride_r = 1;
  if (in_sizes[5] == 2 * n_dst) { stride_r = 2; }

  // Workspace layout: xlin [n_src*16] | deg_src [n_src] | deg_dst [n_dst]
  float* xlin    = (float*)d_ws;
  float* deg_src = xlin + (size_t)n_src * D_OUT;
  float* deg_dst = deg_src + n_src;

  (void)hipMemsetAsync(deg_src, 0, (size_t)(n_src + n_dst) * sizeof(float), stream);
  (void)hipMemsetAsync(d_out, 0, (size_t)out_size * sizeof(float), stream);

  // 1) fused x_lin + deg_src
  {
    const int grid = 2048;
    xlin_deg_kernel<<<grid, 256, 0, stream>>>(x, W, xlin, es, deg_src,
                                              n_src, n_e, stride_e, grid);
  }
  // 2) edge scatter into d_out (acts as m) + deg_dst
  {
    long long threads = (long long)n_e * D_OUT;
    int grid = (int)((threads + 255) / 256);
    edge_kernel<<<grid, 256, 0, stream>>>(es, ed, xlin, deg_src, out, deg_dst,
                                          n_e, stride_e);
  }
  // 3) finalize + log-softmax (in place on d_out)
  {
    int threads = n_dst * D_OUT;
    int grid = (threads + 255) / 256;
    finalize_kernel<<<grid, 256, 0, stream>>>(xlin, rn, deg_dst, b, out, n_dst, stride_r);
  }
}